// Round 2
// baseline (482.350 us; speedup 1.0000x reference)
//
#include <hip/hip_runtime.h>

// out[t,b,n] = 1 iff any spike in window [t-duration+1, t], else 0.
// Streaming scan over time; "time of last spike" is the only state.
// float4 vectorization: each thread owns 4 adjacent columns (16 B/lane
// loads+stores). Time split into 16 chunks of 128 with a (duration-1)
// halo re-scan per chunk -> 512 blocks (2 blocks/CU, 8 waves/CU),
// ~32 KB of reads in flight per CU to cover ~900-cyc HBM latency.

#define T_TOTAL 2048
#define M_COLS  (16 * 2048)     // B*N, fastest axis
#define M4      (M_COLS / 4)    // float4 groups per time step
#define CHUNK   128             // time steps per thread

__global__ __launch_bounds__(256) void psp_scan_kernel(
    const float4* __restrict__ x,
    const int*   __restrict__ dur_p,
    float4* __restrict__ out)
{
    const int col = blockIdx.x * blockDim.x + threadIdx.x;   // 0 .. M4-1
    const int t0  = blockIdx.y * CHUNK;
    const int duration = dur_p[0];                           // uniform scalar load

    // sentinel: (t - last) >= duration for all t >= t0 until a real spike
    const int sent = t0 - duration;
    int4 last = make_int4(sent, sent, sent, sent);

    int tstart = t0 - duration + 1;
    if (tstart < 0) tstart = 0;

    const float4* xc = x + col;
    float4* oc = out + col;

    // Halo: recover last-spike state entering this chunk (<= 99 steps).
    #pragma unroll 4
    for (int t = tstart; t < t0; ++t) {
        float4 v = xc[(size_t)t * M4];
        last.x = (v.x != 0.0f) ? t : last.x;
        last.y = (v.y != 0.0f) ? t : last.y;
        last.z = (v.z != 0.0f) ? t : last.z;
        last.w = (v.w != 0.0f) ? t : last.w;
    }

    // Main chunk: scan + emit.
    #pragma unroll 8
    for (int t = t0; t < t0 + CHUNK; ++t) {
        float4 v = xc[(size_t)t * M4];
        last.x = (v.x != 0.0f) ? t : last.x;
        last.y = (v.y != 0.0f) ? t : last.y;
        last.z = (v.z != 0.0f) ? t : last.z;
        last.w = (v.w != 0.0f) ? t : last.w;
        float4 o;
        o.x = (t - last.x < duration) ? 1.0f : 0.0f;
        o.y = (t - last.y < duration) ? 1.0f : 0.0f;
        o.z = (t - last.z < duration) ? 1.0f : 0.0f;
        o.w = (t - last.w < duration) ? 1.0f : 0.0f;
        oc[(size_t)t * M4] = o;
    }
}

extern "C" void kernel_launch(void* const* d_in, const int* in_sizes, int n_in,
                              void* d_out, int out_size, void* d_ws, size_t ws_size,
                              hipStream_t stream) {
    const float4* x     = (const float4*)d_in[0];
    const int*    dur_p = (const int*)d_in[1];
    float4*       out   = (float4*)d_out;

    dim3 grid(M4 / 256, T_TOTAL / CHUNK);   // (32, 16) = 512 blocks
    dim3 block(256);
    psp_scan_kernel<<<grid, block, 0, stream>>>(x, dur_p, out);
}

// Round 3
// 457.256 us; speedup vs baseline: 1.0549x; 1.0549x over previous
//
#include <hip/hip_runtime.h>

// out[t,b,n] = 1 iff any spike in window [t-duration+1, t], else 0.
// Streaming scan over time; state = time of last spike per column.
//
// R3: MLP-focused. Scalar 4B columns (one col per thread, coalesced
// 256B per wave-load). Time split into 16 chunks of 128 (2048 blocks =
// 8 blocks/CU = up to 32 waves/CU). Inside the chunk, loads are issued
// in explicit batches of 16 independent global_load_dword before any
// consumer, giving ~4KB in flight per wave; with ~20+ resident waves/CU
// that is >80KB/CU in flight vs the ~4KB that latency-bound R1/R2.

#define T_TOTAL 2048
#define M_COLS  (16 * 2048)   // B*N, fastest axis
#define CHUNK   128           // time steps per thread chunk
#define BATCH   16            // loads in flight per wave

__global__ __launch_bounds__(256, 8) void psp_scan_kernel(
    const float* __restrict__ x,
    const int*  __restrict__ dur_p,
    float* __restrict__ out)
{
    const int col = blockIdx.x * blockDim.x + threadIdx.x;   // 0 .. M_COLS-1
    const int t0  = blockIdx.y * CHUNK;
    const int duration = dur_p[0];                           // uniform

    int last = t0 - duration;   // sentinel: no spike yet in window
    int tstart = t0 - duration + 1;
    if (tstart < 0) tstart = 0;

    const float* xc = x + col;
    float* oc = out + col;

    // ---- Halo: recover last-spike state entering this chunk (<= 99 steps) ----
    int t = tstart;
    for (; t + BATCH <= t0; t += BATCH) {
        float v[BATCH];
        #pragma unroll
        for (int i = 0; i < BATCH; ++i) v[i] = xc[(size_t)(t + i) * M_COLS];
        #pragma unroll
        for (int i = 0; i < BATCH; ++i) {
            if (v[i] != 0.0f) last = t + i;
        }
    }
    for (; t < t0; ++t) {
        float v = xc[(size_t)t * M_COLS];
        if (v != 0.0f) last = t;
    }

    // ---- Main chunk: batched load -> scan -> batched store ----
    for (int tb = t0; tb < t0 + CHUNK; tb += BATCH) {
        float v[BATCH];
        #pragma unroll
        for (int i = 0; i < BATCH; ++i) v[i] = xc[(size_t)(tb + i) * M_COLS];

        float o[BATCH];
        #pragma unroll
        for (int i = 0; i < BATCH; ++i) {
            const int tt = tb + i;
            last = (v[i] != 0.0f) ? tt : last;
            o[i] = (tt - last < duration) ? 1.0f : 0.0f;
        }

        #pragma unroll
        for (int i = 0; i < BATCH; ++i) oc[(size_t)(tb + i) * M_COLS] = o[i];
    }
}

extern "C" void kernel_launch(void* const* d_in, const int* in_sizes, int n_in,
                              void* d_out, int out_size, void* d_ws, size_t ws_size,
                              hipStream_t stream) {
    const float* x     = (const float*)d_in[0];
    const int*   dur_p = (const int*)d_in[1];
    float*       out   = (float*)d_out;

    dim3 grid(M_COLS / 256, T_TOTAL / CHUNK);   // (128, 16) = 2048 blocks
    dim3 block(256);
    psp_scan_kernel<<<grid, block, 0, stream>>>(x, dur_p, out);
}